// Round 1
// baseline (3329.439 us; speedup 1.0000x reference)
//
#include <hip/hip_runtime.h>

#define NN 100000
#define NE 1600000
#define DIN 128
#define HD 64
#define NL 4
#define NG 64

// ---------- helpers ----------
__device__ __forceinline__ float wave_sum64(float v) {
#pragma unroll
  for (int off = 1; off < 64; off <<= 1) v += __shfl_xor(v, off, 64);
  return v;
}

// ---------- CSR build ----------
__global__ __launch_bounds__(256) void k_count(const int* __restrict__ dst,
                                               int* __restrict__ counts) {
  int e = blockIdx.x * 256 + threadIdx.x;
  if (e < NE) atomicAdd(&counts[dst[e]], 1);
}

__global__ __launch_bounds__(256) void k_bsum(const int* __restrict__ counts,
                                              int* __restrict__ bsum) {
  __shared__ int s[256];
  int tid = threadIdx.x;
  int i = blockIdx.x * 256 + tid;
  s[tid] = (i < NN) ? counts[i] : 0;
  __syncthreads();
#pragma unroll
  for (int off = 128; off > 0; off >>= 1) {
    if (tid < off) s[tid] += s[tid + off];
    __syncthreads();
  }
  if (tid == 0) bsum[blockIdx.x] = s[0];
}

__global__ __launch_bounds__(512) void k_scanb(const int* __restrict__ bsum,
                                               int* __restrict__ boff, int nb,
                                               int* __restrict__ row_ptr) {
  __shared__ int s[512];
  int t = threadIdx.x;
  int v = (t < nb) ? bsum[t] : 0;
  s[t] = v;
  __syncthreads();
  for (int off = 1; off < 512; off <<= 1) {
    int add = (t >= off) ? s[t - off] : 0;
    __syncthreads();
    s[t] += add;
    __syncthreads();
  }
  if (t < nb) boff[t] = s[t] - v;  // exclusive
  if (t == 0) row_ptr[NN] = NE;
}

__global__ __launch_bounds__(256) void k_scan3(const int* __restrict__ counts,
                                               const int* __restrict__ boff,
                                               int* __restrict__ row_ptr,
                                               int* __restrict__ cursor) {
  __shared__ int s[256];
  int t = threadIdx.x;
  int i = blockIdx.x * 256 + t;
  int v = (i < NN) ? counts[i] : 0;
  s[t] = v;
  __syncthreads();
  for (int off = 1; off < 256; off <<= 1) {
    int add = (t >= off) ? s[t - off] : 0;
    __syncthreads();
    s[t] += add;
    __syncthreads();
  }
  int rp = boff[blockIdx.x] + s[t] - v;  // exclusive
  if (i < NN) {
    row_ptr[i] = rp;
    cursor[i] = rp;
  }
}

__global__ __launch_bounds__(256) void k_fill(const int* __restrict__ src,
                                              const int* __restrict__ dst,
                                              int* __restrict__ cursor,
                                              int* __restrict__ csr_src) {
  int e = blockIdx.x * 256 + threadIdx.x;
  if (e < NE) {
    int d = dst[e];
    int pos = atomicAdd(&cursor[d], 1);
    csr_src[pos] = src[e];
  }
}

// ---------- encoder: h = x @ W^T + b ; hn = relu(LN_0(h)) ----------
__global__ __launch_bounds__(256) void k_encoder(
    const float* __restrict__ x, const float* __restrict__ W,
    const float* __restrict__ bias, const float* __restrict__ lng,
    const float* __restrict__ lnb, float* __restrict__ h,
    float* __restrict__ hn) {
  __shared__ float xs[64 * DIN];
  const int tid = threadIdx.x, lane = tid & 63, wave = tid >> 6;
  const int nbase = blockIdx.x * 64;
  const int nvalid = min(64, NN - nbase);
  const float4* xg = (const float4*)(x + (size_t)nbase * DIN);
  for (int i = tid; i < nvalid * (DIN / 4); i += 256) ((float4*)xs)[i] = xg[i];
  __syncthreads();

  float acc[16];
  const float bv = bias[lane];
#pragma unroll
  for (int m = 0; m < 16; m++) acc[m] = bv;
  const float* wrow = W + lane * DIN;
  for (int kc = 0; kc < DIN; kc += 64) {
    float4 w4[16];
#pragma unroll
    for (int kk = 0; kk < 16; kk++)
      w4[kk] = *(const float4*)(wrow + kc + kk * 4);
#pragma unroll
    for (int kk = 0; kk < 16; kk++) {
#pragma unroll
      for (int m = 0; m < 16; m++) {
        float4 zv = *(const float4*)(xs + (wave * 16 + m) * DIN + kc + kk * 4);
        acc[m] = fmaf(zv.x, w4[kk].x, acc[m]);
        acc[m] = fmaf(zv.y, w4[kk].y, acc[m]);
        acc[m] = fmaf(zv.z, w4[kk].z, acc[m]);
        acc[m] = fmaf(zv.w, w4[kk].w, acc[m]);
      }
    }
  }
  const float g = lng[lane], bb = lnb[lane];
#pragma unroll
  for (int m = 0; m < 16; m++) {
    int nl = wave * 16 + m;
    int node = nbase + nl;
    float v = acc[m];
    float mu = wave_sum64(v) * (1.f / 64.f);
    float d = v - mu;
    float var = wave_sum64(d * d) * (1.f / 64.f);
    float y = d * rsqrtf(var + 1e-5f) * g + bb;
    if (nl < nvalid) {
      h[(size_t)node * HD + lane] = v;
      hn[(size_t)node * HD + lane] = fmaxf(y, 0.f);
    }
  }
}

// ---------- aggregation: z0 = (1+eps)*hn + sum_{src in CSR[dst]} hn[src] ----
__global__ __launch_bounds__(256) void k_agg(const float* __restrict__ hn,
                                             const int* __restrict__ row_ptr,
                                             const int* __restrict__ csr_src,
                                             const float* __restrict__ eps_arr,
                                             int layer,
                                             float* __restrict__ z0) {
  const int lane = threadIdx.x & 63, wave = threadIdx.x >> 6;
  const int node = blockIdx.x * 4 + wave;
  if (node >= NN) return;
  const float e = 1.f + eps_arr[layer];
  float acc = hn[(size_t)node * HD + lane] * e;
  const int s0 = row_ptr[node], s1 = row_ptr[node + 1];
  for (int j = s0; j < s1; j++) {
    int s = csr_src[j];
    acc += hn[(size_t)s * HD + lane];
  }
  z0[(size_t)node * HD + lane] = acc;
}

// ---------- fused MLP: z1=relu(bn1(z0@w1^T+b1)); z2=relu(bn2(z1@w2^T+b2));
//            h += z2; hn = relu(LN_{l+1}(h)) if do_ln ----------
__global__ __launch_bounds__(256) void k_mlp(
    const float* __restrict__ z0, float* __restrict__ h,
    float* __restrict__ hn, const float* __restrict__ w1,
    const float* __restrict__ b1, const float* __restrict__ g1,
    const float* __restrict__ bb1, const float* __restrict__ m1,
    const float* __restrict__ v1, const float* __restrict__ w2,
    const float* __restrict__ b2, const float* __restrict__ g2,
    const float* __restrict__ bb2, const float* __restrict__ m2,
    const float* __restrict__ v2, const float* __restrict__ lng,
    const float* __restrict__ lnb, int do_ln) {
  __shared__ float zs[64 * HD];
  __shared__ float z1s[64 * HD];
  const int tid = threadIdx.x, lane = tid & 63, wave = tid >> 6;
  const int nbase = blockIdx.x * 64;
  const int nvalid = min(64, NN - nbase);
  const float4* zg = (const float4*)(z0 + (size_t)nbase * HD);
  for (int i = tid; i < nvalid * (HD / 4); i += 256) ((float4*)zs)[i] = zg[i];
  __syncthreads();

  const float a1 = g1[lane] * rsqrtf(v1[lane] + 1e-5f);
  const float c1 = (b1[lane] - m1[lane]) * a1 + bb1[lane];
  float acc[16];
#pragma unroll
  for (int m = 0; m < 16; m++) acc[m] = 0.f;
  {
    float4 w4[16];
    const float* wrow = w1 + lane * HD;
#pragma unroll
    for (int kk = 0; kk < 16; kk++) w4[kk] = *(const float4*)(wrow + kk * 4);
#pragma unroll
    for (int kk = 0; kk < 16; kk++) {
#pragma unroll
      for (int m = 0; m < 16; m++) {
        float4 zv = *(const float4*)(zs + (wave * 16 + m) * HD + kk * 4);
        acc[m] = fmaf(zv.x, w4[kk].x, acc[m]);
        acc[m] = fmaf(zv.y, w4[kk].y, acc[m]);
        acc[m] = fmaf(zv.z, w4[kk].z, acc[m]);
        acc[m] = fmaf(zv.w, w4[kk].w, acc[m]);
      }
    }
  }
#pragma unroll
  for (int m = 0; m < 16; m++) {
    float z1v = fmaxf(fmaf(acc[m], a1, c1), 0.f);
    z1s[(wave * 16 + m) * HD + lane] = z1v;
  }
  __syncthreads();

  const float a2 = g2[lane] * rsqrtf(v2[lane] + 1e-5f);
  const float c2 = (b2[lane] - m2[lane]) * a2 + bb2[lane];
#pragma unroll
  for (int m = 0; m < 16; m++) acc[m] = 0.f;
  {
    float4 w4[16];
    const float* wrow = w2 + lane * HD;
#pragma unroll
    for (int kk = 0; kk < 16; kk++) w4[kk] = *(const float4*)(wrow + kk * 4);
#pragma unroll
    for (int kk = 0; kk < 16; kk++) {
#pragma unroll
      for (int m = 0; m < 16; m++) {
        float4 zv = *(const float4*)(z1s + (wave * 16 + m) * HD + kk * 4);
        acc[m] = fmaf(zv.x, w4[kk].x, acc[m]);
        acc[m] = fmaf(zv.y, w4[kk].y, acc[m]);
        acc[m] = fmaf(zv.z, w4[kk].z, acc[m]);
        acc[m] = fmaf(zv.w, w4[kk].w, acc[m]);
      }
    }
  }

  const float g = lng[lane], bbv = lnb[lane];
#pragma unroll
  for (int m = 0; m < 16; m++) {
    int nl = wave * 16 + m;
    int node = nbase + nl;
    float hv = (nl < nvalid) ? h[(size_t)node * HD + lane] : 0.f;
    float z2v = fmaxf(fmaf(acc[m], a2, c2), 0.f);
    float v = hv + z2v;
    if (nl < nvalid) h[(size_t)node * HD + lane] = v;
    if (do_ln) {
      float mu = wave_sum64(v) * (1.f / 64.f);
      float d = v - mu;
      float var = wave_sum64(d * d) * (1.f / 64.f);
      float y = d * rsqrtf(var + 1e-5f) * g + bbv;
      if (nl < nvalid) hn[(size_t)node * HD + lane] = fmaxf(y, 0.f);
    }
  }
}

// ---------- pooling ----------
__global__ __launch_bounds__(256) void k_pool(const float* __restrict__ h,
                                              const int* __restrict__ batch,
                                              float* __restrict__ sums,
                                              float* __restrict__ cnt) {
  const int lane = threadIdx.x & 63;
  const int gw = blockIdx.x * 4 + (threadIdx.x >> 6);
  const int base = gw * 64;
  if (base >= NN) return;
  const int end = min(base + 64, NN);
  float acc = 0.f;
  int cur = batch[base];
  int runlen = 0;
  for (int n = base; n < end; n++) {
    int g = batch[n];
    if (g != cur) {
      atomicAdd(&sums[cur * HD + lane], acc);
      if (lane == 0) atomicAdd(&cnt[cur], (float)runlen);
      acc = 0.f;
      runlen = 0;
      cur = g;
    }
    acc += h[(size_t)n * HD + lane];
    runlen++;
  }
  atomicAdd(&sums[cur * HD + lane], acc);
  if (lane == 0) atomicAdd(&cnt[cur], (float)runlen);
}

__global__ __launch_bounds__(256) void k_div(const float* __restrict__ sums,
                                             const float* __restrict__ cnt,
                                             float* __restrict__ out) {
  int i = blockIdx.x * 256 + threadIdx.x;
  if (i < NG * HD) out[i] = sums[i] / fmaxf(cnt[i >> 6], 1.f);
}

// ---------- launch ----------
extern "C" void kernel_launch(void* const* d_in, const int* in_sizes, int n_in,
                              void* d_out, int out_size, void* d_ws,
                              size_t ws_size, hipStream_t stream) {
  const float* x = (const float*)d_in[0];
  const float* node_w = (const float*)d_in[1];
  const float* node_b = (const float*)d_in[2];
  const float* ln_g = (const float*)d_in[3];
  const float* ln_b = (const float*)d_in[4];
  const float* eps = (const float*)d_in[5];
  const float* w1 = (const float*)d_in[6];
  const float* b1 = (const float*)d_in[7];
  const float* bn1_g = (const float*)d_in[8];
  const float* bn1_b = (const float*)d_in[9];
  const float* bn1_m = (const float*)d_in[10];
  const float* bn1_v = (const float*)d_in[11];
  const float* w2 = (const float*)d_in[12];
  const float* b2 = (const float*)d_in[13];
  const float* bn2_g = (const float*)d_in[14];
  const float* bn2_b = (const float*)d_in[15];
  const float* bn2_m = (const float*)d_in[16];
  const float* bn2_v = (const float*)d_in[17];
  const int* edge_index = (const int*)d_in[18];
  const int* batch = (const int*)d_in[19];
  float* out = (float*)d_out;

  char* ws = (char*)d_ws;
  size_t off = 0;
  auto carve = [&](size_t bytes) {
    void* p = ws + off;
    off += (bytes + 255) & ~(size_t)255;
    return p;
  };
  const size_t NHB = (size_t)NN * HD * sizeof(float);
  float* h = (float*)carve(NHB);
  float* hn = (float*)carve(NHB);
  float* z0 = (float*)carve(NHB);
  int* csr_src = (int*)carve((size_t)NE * sizeof(int));
  int* row_ptr = (int*)carve((size_t)(NN + 1) * sizeof(int));
  int* cursor = (int*)carve((size_t)NN * sizeof(int));
  int* counts = (int*)carve((size_t)NN * sizeof(int));
  int* bsum = (int*)carve(512 * sizeof(int));
  int* boff = (int*)carve(512 * sizeof(int));
  float* sums = (float*)carve((size_t)NG * HD * sizeof(float));
  float* cnt = (float*)carve((size_t)NG * sizeof(float));

  const int NB = (NN + 255) / 256;  // 391

  hipMemsetAsync(counts, 0, (size_t)NN * sizeof(int), stream);
  hipMemsetAsync(sums, 0, (size_t)NG * HD * sizeof(float), stream);
  hipMemsetAsync(cnt, 0, (size_t)NG * sizeof(float), stream);

  const int* e_src = edge_index;
  const int* e_dst = edge_index + NE;

  k_count<<<(NE + 255) / 256, 256, 0, stream>>>(e_dst, counts);
  k_bsum<<<NB, 256, 0, stream>>>(counts, bsum);
  k_scanb<<<1, 512, 0, stream>>>(bsum, boff, NB, row_ptr);
  k_scan3<<<NB, 256, 0, stream>>>(counts, boff, row_ptr, cursor);
  k_fill<<<(NE + 255) / 256, 256, 0, stream>>>(e_src, e_dst, cursor, csr_src);

  k_encoder<<<(NN + 63) / 64, 256, 0, stream>>>(x, node_w, node_b, ln_g, ln_b,
                                                h, hn);

  for (int l = 0; l < NL; l++) {
    k_agg<<<(NN + 3) / 4, 256, 0, stream>>>(hn, row_ptr, csr_src, eps, l, z0);
    int do_ln = (l < NL - 1) ? 1 : 0;
    const float* lg = do_ln ? (ln_g + (l + 1) * HD) : ln_g;
    const float* lb = do_ln ? (ln_b + (l + 1) * HD) : ln_b;
    k_mlp<<<(NN + 63) / 64, 256, 0, stream>>>(
        z0, h, hn, w1 + (size_t)l * HD * HD, b1 + l * HD, bn1_g + l * HD,
        bn1_b + l * HD, bn1_m + l * HD, bn1_v + l * HD,
        w2 + (size_t)l * HD * HD, b2 + l * HD, bn2_g + l * HD, bn2_b + l * HD,
        bn2_m + l * HD, bn2_v + l * HD, lg, lb, do_ln);
  }

  k_pool<<<NB, 256, 0, stream>>>(h, batch, sums, cnt);
  k_div<<<(NG * HD + 255) / 256, 256, 0, stream>>>(sums, cnt, out);
}

// Round 2
// 1262.687 us; speedup vs baseline: 2.6368x; 2.6368x over previous
//
#include <hip/hip_runtime.h>

#define NN 100000
#define NE 1600000
#define DIN 128
#define HD 64
#define NL 4
#define NG 64

// ---------- helpers ----------
__device__ __forceinline__ float wave_sum64(float v) {
#pragma unroll
  for (int off = 1; off < 64; off <<= 1) v += __shfl_xor(v, off, 64);
  return v;
}

// ---------- CSR build ----------
__global__ __launch_bounds__(256) void k_count(const int* __restrict__ dst,
                                               int* __restrict__ counts) {
  int e = blockIdx.x * 256 + threadIdx.x;
  if (e < NE) atomicAdd(&counts[dst[e]], 1);
}

__global__ __launch_bounds__(256) void k_bsum(const int* __restrict__ counts,
                                              int* __restrict__ bsum) {
  __shared__ int s[256];
  int tid = threadIdx.x;
  int i = blockIdx.x * 256 + tid;
  s[tid] = (i < NN) ? counts[i] : 0;
  __syncthreads();
#pragma unroll
  for (int off = 128; off > 0; off >>= 1) {
    if (tid < off) s[tid] += s[tid + off];
    __syncthreads();
  }
  if (tid == 0) bsum[blockIdx.x] = s[0];
}

__global__ __launch_bounds__(512) void k_scanb(const int* __restrict__ bsum,
                                               int* __restrict__ boff, int nb,
                                               int* __restrict__ row_ptr) {
  __shared__ int s[512];
  int t = threadIdx.x;
  int v = (t < nb) ? bsum[t] : 0;
  s[t] = v;
  __syncthreads();
  for (int off = 1; off < 512; off <<= 1) {
    int add = (t >= off) ? s[t - off] : 0;
    __syncthreads();
    s[t] += add;
    __syncthreads();
  }
  if (t < nb) boff[t] = s[t] - v;  // exclusive
  if (t == 0) row_ptr[NN] = NE;
}

__global__ __launch_bounds__(256) void k_scan3(const int* __restrict__ counts,
                                               const int* __restrict__ boff,
                                               int* __restrict__ row_ptr,
                                               int* __restrict__ cursor) {
  __shared__ int s[256];
  int t = threadIdx.x;
  int i = blockIdx.x * 256 + t;
  int v = (i < NN) ? counts[i] : 0;
  s[t] = v;
  __syncthreads();
  for (int off = 1; off < 256; off <<= 1) {
    int add = (t >= off) ? s[t - off] : 0;
    __syncthreads();
    s[t] += add;
    __syncthreads();
  }
  int rp = boff[blockIdx.x] + s[t] - v;  // exclusive
  if (i < NN) {
    row_ptr[i] = rp;
    cursor[i] = rp;
  }
}

__global__ __launch_bounds__(256) void k_fill(const int* __restrict__ src,
                                              const int* __restrict__ dst,
                                              int* __restrict__ cursor,
                                              int* __restrict__ csr_src) {
  int e = blockIdx.x * 256 + threadIdx.x;
  if (e < NE) {
    int d = dst[e];
    int pos = atomicAdd(&cursor[d], 1);
    csr_src[pos] = src[e];
  }
}

// GEMM inner: out[n][lane] = sum_k in[n][k] * w[lane][k], spill-safe.
// acc/w4/zv all statically indexed; sched_barrier(0) bounds the scheduler's
// hoisting window to one m-iteration (prevents 256-load hoist -> scratch).
#define GEMM_CHUNK(ZS, LDIM, KC, ACC, W4)                              \
  {                                                                    \
    _Pragma("unroll") for (int m = 0; m < 16; m++) {                   \
      const float* zr = (ZS) + (wave * 16 + m) * (LDIM) + (KC);        \
      float a = ACC[m];                                                \
      _Pragma("unroll") for (int q = 0; q < 8; q++) {                  \
        float4 zv = *(const float4*)(zr + q * 4);                      \
        a = fmaf(zv.x, W4[q].x, a);                                    \
        a = fmaf(zv.y, W4[q].y, a);                                    \
        a = fmaf(zv.z, W4[q].z, a);                                    \
        a = fmaf(zv.w, W4[q].w, a);                                    \
      }                                                                \
      ACC[m] = a;                                                      \
      __builtin_amdgcn_sched_barrier(0);                               \
    }                                                                  \
  }

// ---------- encoder: h = x @ W^T + b ; hn = relu(LN_0(h)) ----------
__global__ __launch_bounds__(256) void k_encoder(
    const float* __restrict__ x, const float* __restrict__ W,
    const float* __restrict__ bias, const float* __restrict__ lng,
    const float* __restrict__ lnb, float* __restrict__ h,
    float* __restrict__ hn) {
  __shared__ float xs[64 * DIN];
  const int tid = threadIdx.x, lane = tid & 63, wave = tid >> 6;
  const int nbase = blockIdx.x * 64;
  const int nvalid = min(64, NN - nbase);
  const float4* xg = (const float4*)(x + (size_t)nbase * DIN);
  for (int i = tid; i < nvalid * (DIN / 4); i += 256) ((float4*)xs)[i] = xg[i];
  __syncthreads();

  float acc[16];
  const float bv = bias[lane];
#pragma unroll
  for (int m = 0; m < 16; m++) acc[m] = bv;
  const float* wrow = W + lane * DIN;
#pragma unroll 1
  for (int kc = 0; kc < DIN; kc += 32) {
    float4 w4[8];
#pragma unroll
    for (int q = 0; q < 8; q++) w4[q] = *(const float4*)(wrow + kc + q * 4);
    GEMM_CHUNK(xs, DIN, kc, acc, w4)
  }

  const float g = lng[lane], bb = lnb[lane];
#pragma unroll
  for (int m = 0; m < 16; m++) {
    int nl = wave * 16 + m;
    int node = nbase + nl;
    float v = acc[m];
    float mu = wave_sum64(v) * (1.f / 64.f);
    float d = v - mu;
    float var = wave_sum64(d * d) * (1.f / 64.f);
    float y = d * rsqrtf(var + 1e-5f) * g + bb;
    if (nl < nvalid) {
      h[(size_t)node * HD + lane] = v;
      hn[(size_t)node * HD + lane] = fmaxf(y, 0.f);
    }
  }
}

// ---------- aggregation: z0 = (1+eps)*hn + sum_{src in CSR[dst]} hn[src] ----
__global__ __launch_bounds__(256) void k_agg(const float* __restrict__ hn,
                                             const int* __restrict__ row_ptr,
                                             const int* __restrict__ csr_src,
                                             const float* __restrict__ eps_arr,
                                             int layer,
                                             float* __restrict__ z0) {
  const int lane = threadIdx.x & 63, wave = threadIdx.x >> 6;
  const int node = blockIdx.x * 4 + wave;
  if (node >= NN) return;
  const float e = 1.f + eps_arr[layer];
  float acc = hn[(size_t)node * HD + lane] * e;
  const int s0 = row_ptr[node], s1 = row_ptr[node + 1];
  for (int j = s0; j < s1; j++) {
    int s = csr_src[j];
    acc += hn[(size_t)s * HD + lane];
  }
  z0[(size_t)node * HD + lane] = acc;
}

// ---------- fused MLP: z1=relu(bn1(z0@w1^T+b1)); z2=relu(bn2(z1@w2^T+b2));
//            h += z2; hn = relu(LN_{l+1}(h)) if do_ln ----------
__global__ __launch_bounds__(256) void k_mlp(
    const float* __restrict__ z0, float* __restrict__ h,
    float* __restrict__ hn, const float* __restrict__ w1,
    const float* __restrict__ b1, const float* __restrict__ g1,
    const float* __restrict__ bb1, const float* __restrict__ m1,
    const float* __restrict__ v1, const float* __restrict__ w2,
    const float* __restrict__ b2, const float* __restrict__ g2,
    const float* __restrict__ bb2, const float* __restrict__ m2,
    const float* __restrict__ v2, const float* __restrict__ lng,
    const float* __restrict__ lnb, int do_ln) {
  __shared__ float zs[64 * HD];
  __shared__ float z1s[64 * HD];
  const int tid = threadIdx.x, lane = tid & 63, wave = tid >> 6;
  const int nbase = blockIdx.x * 64;
  const int nvalid = min(64, NN - nbase);
  const float4* zg = (const float4*)(z0 + (size_t)nbase * HD);
  for (int i = tid; i < nvalid * (HD / 4); i += 256) ((float4*)zs)[i] = zg[i];
  __syncthreads();

  const float a1 = g1[lane] * rsqrtf(v1[lane] + 1e-5f);
  const float c1 = (b1[lane] - m1[lane]) * a1 + bb1[lane];
  float acc[16];
#pragma unroll
  for (int m = 0; m < 16; m++) acc[m] = 0.f;
  {
    const float* wrow = w1 + lane * HD;
#pragma unroll 1
    for (int kc = 0; kc < HD; kc += 32) {
      float4 w4[8];
#pragma unroll
      for (int q = 0; q < 8; q++) w4[q] = *(const float4*)(wrow + kc + q * 4);
      GEMM_CHUNK(zs, HD, kc, acc, w4)
    }
  }
#pragma unroll
  for (int m = 0; m < 16; m++) {
    float z1v = fmaxf(fmaf(acc[m], a1, c1), 0.f);
    z1s[(wave * 16 + m) * HD + lane] = z1v;
  }
  __syncthreads();

  const float a2 = g2[lane] * rsqrtf(v2[lane] + 1e-5f);
  const float c2 = (b2[lane] - m2[lane]) * a2 + bb2[lane];
#pragma unroll
  for (int m = 0; m < 16; m++) acc[m] = 0.f;
  {
    const float* wrow = w2 + lane * HD;
#pragma unroll 1
    for (int kc = 0; kc < HD; kc += 32) {
      float4 w4[8];
#pragma unroll
      for (int q = 0; q < 8; q++) w4[q] = *(const float4*)(wrow + kc + q * 4);
      GEMM_CHUNK(z1s, HD, kc, acc, w4)
    }
  }

  const float g = lng[lane], bbv = lnb[lane];
#pragma unroll
  for (int m = 0; m < 16; m++) {
    int nl = wave * 16 + m;
    int node = nbase + nl;
    float hv = (nl < nvalid) ? h[(size_t)node * HD + lane] : 0.f;
    float z2v = fmaxf(fmaf(acc[m], a2, c2), 0.f);
    float v = hv + z2v;
    if (nl < nvalid) h[(size_t)node * HD + lane] = v;
    if (do_ln) {
      float mu = wave_sum64(v) * (1.f / 64.f);
      float d = v - mu;
      float var = wave_sum64(d * d) * (1.f / 64.f);
      float y = d * rsqrtf(var + 1e-5f) * g + bbv;
      if (nl < nvalid) hn[(size_t)node * HD + lane] = fmaxf(y, 0.f);
    }
  }
}

// ---------- pooling ----------
__global__ __launch_bounds__(256) void k_pool(const float* __restrict__ h,
                                              const int* __restrict__ batch,
                                              float* __restrict__ sums,
                                              float* __restrict__ cnt) {
  const int lane = threadIdx.x & 63;
  const int gw = blockIdx.x * 4 + (threadIdx.x >> 6);
  const int base = gw * 64;
  if (base >= NN) return;
  const int end = min(base + 64, NN);
  float acc = 0.f;
  int cur = batch[base];
  int runlen = 0;
  for (int n = base; n < end; n++) {
    int g = batch[n];
    if (g != cur) {
      atomicAdd(&sums[cur * HD + lane], acc);
      if (lane == 0) atomicAdd(&cnt[cur], (float)runlen);
      acc = 0.f;
      runlen = 0;
      cur = g;
    }
    acc += h[(size_t)n * HD + lane];
    runlen++;
  }
  atomicAdd(&sums[cur * HD + lane], acc);
  if (lane == 0) atomicAdd(&cnt[cur], (float)runlen);
}

__global__ __launch_bounds__(256) void k_div(const float* __restrict__ sums,
                                             const float* __restrict__ cnt,
                                             float* __restrict__ out) {
  int i = blockIdx.x * 256 + threadIdx.x;
  if (i < NG * HD) out[i] = sums[i] / fmaxf(cnt[i >> 6], 1.f);
}

// ---------- launch ----------
extern "C" void kernel_launch(void* const* d_in, const int* in_sizes, int n_in,
                              void* d_out, int out_size, void* d_ws,
                              size_t ws_size, hipStream_t stream) {
  const float* x = (const float*)d_in[0];
  const float* node_w = (const float*)d_in[1];
  const float* node_b = (const float*)d_in[2];
  const float* ln_g = (const float*)d_in[3];
  const float* ln_b = (const float*)d_in[4];
  const float* eps = (const float*)d_in[5];
  const float* w1 = (const float*)d_in[6];
  const float* b1 = (const float*)d_in[7];
  const float* bn1_g = (const float*)d_in[8];
  const float* bn1_b = (const float*)d_in[9];
  const float* bn1_m = (const float*)d_in[10];
  const float* bn1_v = (const float*)d_in[11];
  const float* w2 = (const float*)d_in[12];
  const float* b2 = (const float*)d_in[13];
  const float* bn2_g = (const float*)d_in[14];
  const float* bn2_b = (const float*)d_in[15];
  const float* bn2_m = (const float*)d_in[16];
  const float* bn2_v = (const float*)d_in[17];
  const int* edge_index = (const int*)d_in[18];
  const int* batch = (const int*)d_in[19];
  float* out = (float*)d_out;

  char* ws = (char*)d_ws;
  size_t off = 0;
  auto carve = [&](size_t bytes) {
    void* p = ws + off;
    off += (bytes + 255) & ~(size_t)255;
    return p;
  };
  const size_t NHB = (size_t)NN * HD * sizeof(float);
  float* h = (float*)carve(NHB);
  float* hn = (float*)carve(NHB);
  float* z0 = (float*)carve(NHB);
  int* csr_src = (int*)carve((size_t)NE * sizeof(int));
  int* row_ptr = (int*)carve((size_t)(NN + 1) * sizeof(int));
  int* cursor = (int*)carve((size_t)NN * sizeof(int));
  int* counts = (int*)carve((size_t)NN * sizeof(int));
  int* bsum = (int*)carve(512 * sizeof(int));
  int* boff = (int*)carve(512 * sizeof(int));
  float* sums = (float*)carve((size_t)NG * HD * sizeof(float));
  float* cnt = (float*)carve((size_t)NG * sizeof(float));

  const int NB = (NN + 255) / 256;  // 391

  hipMemsetAsync(counts, 0, (size_t)NN * sizeof(int), stream);
  hipMemsetAsync(sums, 0, (size_t)NG * HD * sizeof(float), stream);
  hipMemsetAsync(cnt, 0, (size_t)NG * sizeof(float), stream);

  const int* e_src = edge_index;
  const int* e_dst = edge_index + NE;

  k_count<<<(NE + 255) / 256, 256, 0, stream>>>(e_dst, counts);
  k_bsum<<<NB, 256, 0, stream>>>(counts, bsum);
  k_scanb<<<1, 512, 0, stream>>>(bsum, boff, NB, row_ptr);
  k_scan3<<<NB, 256, 0, stream>>>(counts, boff, row_ptr, cursor);
  k_fill<<<(NE + 255) / 256, 256, 0, stream>>>(e_src, e_dst, cursor, csr_src);

  k_encoder<<<(NN + 63) / 64, 256, 0, stream>>>(x, node_w, node_b, ln_g, ln_b,
                                                h, hn);

  for (int l = 0; l < NL; l++) {
    k_agg<<<(NN + 3) / 4, 256, 0, stream>>>(hn, row_ptr, csr_src, eps, l, z0);
    int do_ln = (l < NL - 1) ? 1 : 0;
    const float* lg = do_ln ? (ln_g + (l + 1) * HD) : ln_g;
    const float* lb = do_ln ? (ln_b + (l + 1) * HD) : ln_b;
    k_mlp<<<(NN + 63) / 64, 256, 0, stream>>>(
        z0, h, hn, w1 + (size_t)l * HD * HD, b1 + l * HD, bn1_g + l * HD,
        bn1_b + l * HD, bn1_m + l * HD, bn1_v + l * HD,
        w2 + (size_t)l * HD * HD, b2 + l * HD, bn2_g + l * HD, bn2_b + l * HD,
        bn2_m + l * HD, bn2_v + l * HD, lg, lb, do_ln);
  }

  k_pool<<<NB, 256, 0, stream>>>(h, batch, sums, cnt);
  k_div<<<(NG * HD + 255) / 256, 256, 0, stream>>>(sums, cnt, out);
}

// Round 4
// 1246.005 us; speedup vs baseline: 2.6721x; 1.0134x over previous
//
#include <hip/hip_runtime.h>
#include <hip/hip_fp16.h>

#define NN 100000
#define NE 1600000
#define DIN 128
#define HD 64
#define NL 4
#define NG 64

// ---------- helpers ----------
__device__ __forceinline__ float wave_sum64(float v) {
#pragma unroll
  for (int off = 1; off < 64; off <<= 1) v += __shfl_xor(v, off, 64);
  return v;
}

__device__ __forceinline__ float2 unpack_h2(unsigned w) {
  __half2 hh = *reinterpret_cast<__half2*>(&w);
  return __half22float2(hh);
}

// ---------- CSR build ----------
__global__ __launch_bounds__(256) void k_count(const int* __restrict__ dst,
                                               int* __restrict__ counts) {
  int e = blockIdx.x * 256 + threadIdx.x;
  if (e < NE) atomicAdd(&counts[dst[e]], 1);
}

__global__ __launch_bounds__(256) void k_bsum(const int* __restrict__ counts,
                                              int* __restrict__ bsum) {
  __shared__ int s[256];
  int tid = threadIdx.x;
  int i = blockIdx.x * 256 + tid;
  s[tid] = (i < NN) ? counts[i] : 0;
  __syncthreads();
#pragma unroll
  for (int off = 128; off > 0; off >>= 1) {
    if (tid < off) s[tid] += s[tid + off];
    __syncthreads();
  }
  if (tid == 0) bsum[blockIdx.x] = s[0];
}

__global__ __launch_bounds__(512) void k_scanb(const int* __restrict__ bsum,
                                               int* __restrict__ boff, int nb,
                                               int* __restrict__ row_ptr) {
  __shared__ int s[512];
  int t = threadIdx.x;
  int v = (t < nb) ? bsum[t] : 0;
  s[t] = v;
  __syncthreads();
  for (int off = 1; off < 512; off <<= 1) {
    int add = (t >= off) ? s[t - off] : 0;
    __syncthreads();
    s[t] += add;
    __syncthreads();
  }
  if (t < nb) boff[t] = s[t] - v;  // exclusive
  if (t == 0) row_ptr[NN] = NE;
}

__global__ __launch_bounds__(256) void k_scan3(const int* __restrict__ counts,
                                               const int* __restrict__ boff,
                                               int* __restrict__ row_ptr,
                                               int* __restrict__ cursor) {
  __shared__ int s[256];
  int t = threadIdx.x;
  int i = blockIdx.x * 256 + t;
  int v = (i < NN) ? counts[i] : 0;
  s[t] = v;
  __syncthreads();
  for (int off = 1; off < 256; off <<= 1) {
    int add = (t >= off) ? s[t - off] : 0;
    __syncthreads();
    s[t] += add;
    __syncthreads();
  }
  int rp = boff[blockIdx.x] + s[t] - v;  // exclusive
  if (i < NN) {
    row_ptr[i] = rp;
    cursor[i] = rp;
  }
}

__global__ __launch_bounds__(256) void k_fill(const int* __restrict__ src,
                                              const int* __restrict__ dst,
                                              int* __restrict__ cursor,
                                              int* __restrict__ csr_src) {
  int e = blockIdx.x * 256 + threadIdx.x;
  if (e < NE) {
    int d = dst[e];
    int pos = atomicAdd(&cursor[d], 1);
    csr_src[pos] = src[e];
  }
}

// GEMM inner: spill-safe, statically indexed, hoisting bounded per m-iter.
#define GEMM_CHUNK(ZS, LDIM, KC, ACC, W4)                              \
  {                                                                    \
    _Pragma("unroll") for (int m = 0; m < 16; m++) {                   \
      const float* zr = (ZS) + (wave * 16 + m) * (LDIM) + (KC);        \
      float a = ACC[m];                                                \
      _Pragma("unroll") for (int q = 0; q < 8; q++) {                  \
        float4 zv = *(const float4*)(zr + q * 4);                      \
        a = fmaf(zv.x, W4[q].x, a);                                    \
        a = fmaf(zv.y, W4[q].y, a);                                    \
        a = fmaf(zv.z, W4[q].z, a);                                    \
        a = fmaf(zv.w, W4[q].w, a);                                    \
      }                                                                \
      ACC[m] = a;                                                      \
      __builtin_amdgcn_sched_barrier(0);                               \
    }                                                                  \
  }

// pack feature pair into f16x2 word and store hn2 (even lanes write)
__device__ __forceinline__ void store_hn2(unsigned* __restrict__ hn2, int node,
                                          int lane, float y) {
  float partner = __shfl_xor(y, 1, 64);
  if (!(lane & 1)) {
    __half2 hh = __floats2half2_rn(y, partner);  // lo=feat(lane), hi=feat(lane+1)
    hn2[node * (HD / 2) + (lane >> 1)] = *reinterpret_cast<unsigned*>(&hh);
  }
}

// ---------- encoder: h = x @ W^T + b ; hn2 = f16(relu(LN_0(h))) ----------
__global__ __launch_bounds__(256) void k_encoder(
    const float* __restrict__ x, const float* __restrict__ W,
    const float* __restrict__ bias, const float* __restrict__ lng,
    const float* __restrict__ lnb, float* __restrict__ h,
    unsigned* __restrict__ hn2) {
  __shared__ float xs[64 * DIN];
  const int tid = threadIdx.x, lane = tid & 63, wave = tid >> 6;
  const int nbase = blockIdx.x * 64;
  const int nvalid = min(64, NN - nbase);
  const float4* xg = (const float4*)(x + (size_t)nbase * DIN);
  for (int i = tid; i < nvalid * (DIN / 4); i += 256) ((float4*)xs)[i] = xg[i];
  __syncthreads();

  float acc[16];
  const float bv = bias[lane];
#pragma unroll
  for (int m = 0; m < 16; m++) acc[m] = bv;
  const float* wrow = W + lane * DIN;
#pragma unroll 1
  for (int kc = 0; kc < DIN; kc += 32) {
    float4 w4[8];
#pragma unroll
    for (int q = 0; q < 8; q++) w4[q] = *(const float4*)(wrow + kc + q * 4);
    GEMM_CHUNK(xs, DIN, kc, acc, w4)
  }

  const float g = lng[lane], bb = lnb[lane];
#pragma unroll
  for (int m = 0; m < 16; m++) {
    int nl = wave * 16 + m;
    int node = nbase + nl;
    float v = acc[m];
    float mu = wave_sum64(v) * (1.f / 64.f);
    float d = v - mu;
    float var = wave_sum64(d * d) * (1.f / 64.f);
    float y = fmaxf(d * rsqrtf(var + 1e-5f) * g + bb, 0.f);
    if (nl < nvalid) h[(size_t)node * HD + lane] = v;
    if (nl < nvalid) store_hn2(hn2, node, lane, y);
  }
}

// ---------- fused layer: gather (f16, quarter-wave) + MLP + residual + LN ---
// hn2_in and hn2_out MUST be distinct buffers (cross-block gather races
// against epilogue writes otherwise).
__global__ __launch_bounds__(256) void k_layer(
    const unsigned* __restrict__ hn2_in, float* __restrict__ h,
    unsigned* __restrict__ hn2_out, const int* __restrict__ row_ptr,
    const int* __restrict__ csr_src, const float* __restrict__ eps_arr,
    int layer, const float* __restrict__ w1, const float* __restrict__ b1,
    const float* __restrict__ g1, const float* __restrict__ bb1,
    const float* __restrict__ m1, const float* __restrict__ v1,
    const float* __restrict__ w2, const float* __restrict__ b2,
    const float* __restrict__ g2, const float* __restrict__ bb2,
    const float* __restrict__ m2, const float* __restrict__ v2,
    const float* __restrict__ lng, const float* __restrict__ lnb, int do_ln) {
  __shared__ float zs[64 * HD];
  __shared__ float z1s[64 * HD];
  const int tid = threadIdx.x, lane = tid & 63, wave = tid >> 6;
  const int qtr = lane >> 4, ql = lane & 15;
  const int nbase = blockIdx.x * 64;
  const float e = 1.f + eps_arr[layer];
  const uint2* hnv = (const uint2*)hn2_in;  // 16 uint2 per node row

  // gather: wave w handles nodes nbase+w*16 .. +15; 4 edges in flight
#pragma unroll 1
  for (int mm = 0; mm < 16; mm++) {
    const int node = nbase + wave * 16 + mm;
    if (node >= NN) break;
    float4 acc = make_float4(0.f, 0.f, 0.f, 0.f);
    if (qtr == 0) {  // self term, counted once
      uint2 u = hnv[node * 16 + ql];
      float2 f0 = unpack_h2(u.x), f1 = unpack_h2(u.y);
      acc.x = e * f0.x;
      acc.y = e * f0.y;
      acc.z = e * f1.x;
      acc.w = e * f1.y;
    }
    const int s0 = row_ptr[node], s1 = row_ptr[node + 1];
    for (int j = s0 + qtr; j < s1; j += 4) {
      int s = csr_src[j];
      uint2 u = hnv[s * 16 + ql];
      float2 f0 = unpack_h2(u.x), f1 = unpack_h2(u.y);
      acc.x += f0.x;
      acc.y += f0.y;
      acc.z += f1.x;
      acc.w += f1.y;
    }
    // combine quarters
#pragma unroll
    for (int off = 16; off < 64; off <<= 1) {
      acc.x += __shfl_xor(acc.x, off, 64);
      acc.y += __shfl_xor(acc.y, off, 64);
      acc.z += __shfl_xor(acc.z, off, 64);
      acc.w += __shfl_xor(acc.w, off, 64);
    }
    if (lane < 16)
      *(float4*)(zs + (wave * 16 + mm) * HD + 4 * ql) = acc;
  }
  // no __syncthreads needed: each wave only touches its own 16 rows

  const float a1 = g1[lane] * rsqrtf(v1[lane] + 1e-5f);
  const float c1 = (b1[lane] - m1[lane]) * a1 + bb1[lane];
  float acc[16];
#pragma unroll
  for (int m = 0; m < 16; m++) acc[m] = 0.f;
  {
    const float* wrow = w1 + lane * HD;
#pragma unroll 1
    for (int kc = 0; kc < HD; kc += 32) {
      float4 w4[8];
#pragma unroll
      for (int q = 0; q < 8; q++) w4[q] = *(const float4*)(wrow + kc + q * 4);
      GEMM_CHUNK(zs, HD, kc, acc, w4)
    }
  }
#pragma unroll
  for (int m = 0; m < 16; m++) {
    float z1v = fmaxf(fmaf(acc[m], a1, c1), 0.f);
    z1s[(wave * 16 + m) * HD + lane] = z1v;
  }

  const float a2 = g2[lane] * rsqrtf(v2[lane] + 1e-5f);
  const float c2 = (b2[lane] - m2[lane]) * a2 + bb2[lane];
#pragma unroll
  for (int m = 0; m < 16; m++) acc[m] = 0.f;
  {
    const float* wrow = w2 + lane * HD;
#pragma unroll 1
    for (int kc = 0; kc < HD; kc += 32) {
      float4 w4[8];
#pragma unroll
      for (int q = 0; q < 8; q++) w4[q] = *(const float4*)(wrow + kc + q * 4);
      GEMM_CHUNK(z1s, HD, kc, acc, w4)
    }
  }

  const int nvalid = min(64, NN - nbase);
  const float g = lng[lane], bbv = lnb[lane];
#pragma unroll
  for (int m = 0; m < 16; m++) {
    int nl = wave * 16 + m;
    int node = nbase + nl;
    float hv = (nl < nvalid) ? h[(size_t)node * HD + lane] : 0.f;
    float z2v = fmaxf(fmaf(acc[m], a2, c2), 0.f);
    float v = hv + z2v;
    if (nl < nvalid) h[(size_t)node * HD + lane] = v;
    if (do_ln) {
      float mu = wave_sum64(v) * (1.f / 64.f);
      float d = v - mu;
      float var = wave_sum64(d * d) * (1.f / 64.f);
      float y = fmaxf(d * rsqrtf(var + 1e-5f) * g + bbv, 0.f);
      if (nl < nvalid) store_hn2(hn2_out, node, lane, y);
    }
  }
}

// ---------- pooling ----------
__global__ __launch_bounds__(256) void k_pool(const float* __restrict__ h,
                                              const int* __restrict__ batch,
                                              float* __restrict__ sums,
                                              float* __restrict__ cnt) {
  const int lane = threadIdx.x & 63;
  const int gw = blockIdx.x * 4 + (threadIdx.x >> 6);
  const int base = gw * 64;
  if (base >= NN) return;
  const int end = min(base + 64, NN);
  float acc = 0.f;
  int cur = batch[base];
  int runlen = 0;
  for (int n = base; n < end; n++) {
    int g = batch[n];
    if (g != cur) {
      atomicAdd(&sums[cur * HD + lane], acc);
      if (lane == 0) atomicAdd(&cnt[cur], (float)runlen);
      acc = 0.f;
      runlen = 0;
      cur = g;
    }
    acc += h[(size_t)n * HD + lane];
    runlen++;
  }
  atomicAdd(&sums[cur * HD + lane], acc);
  if (lane == 0) atomicAdd(&cnt[cur], (float)runlen);
}

__global__ __launch_bounds__(256) void k_div(const float* __restrict__ sums,
                                             const float* __restrict__ cnt,
                                             float* __restrict__ out) {
  int i = blockIdx.x * 256 + threadIdx.x;
  if (i < NG * HD) out[i] = sums[i] / fmaxf(cnt[i >> 6], 1.f);
}

// ---------- launch ----------
extern "C" void kernel_launch(void* const* d_in, const int* in_sizes, int n_in,
                              void* d_out, int out_size, void* d_ws,
                              size_t ws_size, hipStream_t stream) {
  const float* x = (const float*)d_in[0];
  const float* node_w = (const float*)d_in[1];
  const float* node_b = (const float*)d_in[2];
  const float* ln_g = (const float*)d_in[3];
  const float* ln_b = (const float*)d_in[4];
  const float* eps = (const float*)d_in[5];
  const float* w1 = (const float*)d_in[6];
  const float* b1 = (const float*)d_in[7];
  const float* bn1_g = (const float*)d_in[8];
  const float* bn1_b = (const float*)d_in[9];
  const float* bn1_m = (const float*)d_in[10];
  const float* bn1_v = (const float*)d_in[11];
  const float* w2 = (const float*)d_in[12];
  const float* b2 = (const float*)d_in[13];
  const float* bn2_g = (const float*)d_in[14];
  const float* bn2_b = (const float*)d_in[15];
  const float* bn2_m = (const float*)d_in[16];
  const float* bn2_v = (const float*)d_in[17];
  const int* edge_index = (const int*)d_in[18];
  const int* batch = (const int*)d_in[19];
  float* out = (float*)d_out;

  char* ws = (char*)d_ws;
  size_t off = 0;
  auto carve = [&](size_t bytes) {
    void* p = ws + off;
    off += (bytes + 255) & ~(size_t)255;
    return p;
  };
  const size_t NHB = (size_t)NN * HD * sizeof(float);
  float* h = (float*)carve(NHB);
  unsigned* hn2a = (unsigned*)carve((size_t)NN * (HD / 2) * sizeof(unsigned));
  unsigned* hn2b = (unsigned*)carve((size_t)NN * (HD / 2) * sizeof(unsigned));
  int* csr_src = (int*)carve((size_t)NE * sizeof(int));
  int* row_ptr = (int*)carve((size_t)(NN + 1) * sizeof(int));
  int* cursor = (int*)carve((size_t)NN * sizeof(int));
  int* counts = (int*)carve((size_t)NN * sizeof(int));
  int* bsum = (int*)carve(512 * sizeof(int));
  int* boff = (int*)carve(512 * sizeof(int));
  float* sums = (float*)carve((size_t)NG * HD * sizeof(float));
  float* cnt = (float*)carve((size_t)NG * sizeof(float));

  const int NB = (NN + 255) / 256;  // 391

  hipMemsetAsync(counts, 0, (size_t)NN * sizeof(int), stream);
  hipMemsetAsync(sums, 0, (size_t)NG * HD * sizeof(float), stream);
  hipMemsetAsync(cnt, 0, (size_t)NG * sizeof(float), stream);

  const int* e_src = edge_index;
  const int* e_dst = edge_index + NE;

  k_count<<<(NE + 255) / 256, 256, 0, stream>>>(e_dst, counts);
  k_bsum<<<NB, 256, 0, stream>>>(counts, bsum);
  k_scanb<<<1, 512, 0, stream>>>(bsum, boff, NB, row_ptr);
  k_scan3<<<NB, 256, 0, stream>>>(counts, boff, row_ptr, cursor);
  k_fill<<<(NE + 255) / 256, 256, 0, stream>>>(e_src, e_dst, cursor, csr_src);

  k_encoder<<<(NN + 63) / 64, 256, 0, stream>>>(x, node_w, node_b, ln_g, ln_b,
                                                h, hn2a);

  for (int l = 0; l < NL; l++) {
    int do_ln = (l < NL - 1) ? 1 : 0;
    const float* lg = do_ln ? (ln_g + (l + 1) * HD) : ln_g;
    const float* lb = do_ln ? (ln_b + (l + 1) * HD) : ln_b;
    const unsigned* hin = (l & 1) ? hn2b : hn2a;
    unsigned* hout = (l & 1) ? hn2a : hn2b;
    k_layer<<<(NN + 63) / 64, 256, 0, stream>>>(
        hin, h, hout, row_ptr, csr_src, eps, l, w1 + (size_t)l * HD * HD,
        b1 + l * HD, bn1_g + l * HD, bn1_b + l * HD, bn1_m + l * HD,
        bn1_v + l * HD, w2 + (size_t)l * HD * HD, b2 + l * HD, bn2_g + l * HD,
        bn2_b + l * HD, bn2_m + l * HD, bn2_v + l * HD, lg, lb, do_ln);
  }

  k_pool<<<NB, 256, 0, stream>>>(h, batch, sums, cnt);
  k_div<<<(NG * HD + 255) / 256, 256, 0, stream>>>(sums, cnt, out);
}

// Round 5
// 786.391 us; speedup vs baseline: 4.2338x; 1.5845x over previous
//
#include <hip/hip_runtime.h>
#include <hip/hip_fp16.h>

#define NN 100000
#define NE 1600000
#define DIN 128
#define HD 64
#define NL 4
#define NG 64

// ---------- helpers ----------
__device__ __forceinline__ float wave_sum64(float v) {
#pragma unroll
  for (int off = 1; off < 64; off <<= 1) v += __shfl_xor(v, off, 64);
  return v;
}

__device__ __forceinline__ float2 unpack_h2(unsigned w) {
  __half2 hh = *reinterpret_cast<__half2*>(&w);
  return __half22float2(hh);
}

// ---------- CSR build ----------
__global__ __launch_bounds__(256) void k_count(const int* __restrict__ dst,
                                               int* __restrict__ counts) {
  int e = blockIdx.x * 256 + threadIdx.x;
  if (e < NE) atomicAdd(&counts[dst[e]], 1);
}

__global__ __launch_bounds__(256) void k_bsum(const int* __restrict__ counts,
                                              int* __restrict__ bsum) {
  __shared__ int s[256];
  int tid = threadIdx.x;
  int i = blockIdx.x * 256 + tid;
  s[tid] = (i < NN) ? counts[i] : 0;
  __syncthreads();
#pragma unroll
  for (int off = 128; off > 0; off >>= 1) {
    if (tid < off) s[tid] += s[tid + off];
    __syncthreads();
  }
  if (tid == 0) bsum[blockIdx.x] = s[0];
}

__global__ __launch_bounds__(512) void k_scanb(const int* __restrict__ bsum,
                                               int* __restrict__ boff, int nb,
                                               int* __restrict__ row_ptr) {
  __shared__ int s[512];
  int t = threadIdx.x;
  int v = (t < nb) ? bsum[t] : 0;
  s[t] = v;
  __syncthreads();
  for (int off = 1; off < 512; off <<= 1) {
    int add = (t >= off) ? s[t - off] : 0;
    __syncthreads();
    s[t] += add;
    __syncthreads();
  }
  if (t < nb) boff[t] = s[t] - v;  // exclusive
  if (t == 0) row_ptr[NN] = NE;
}

__global__ __launch_bounds__(256) void k_scan3(const int* __restrict__ counts,
                                               const int* __restrict__ boff,
                                               int* __restrict__ row_ptr,
                                               int* __restrict__ cursor) {
  __shared__ int s[256];
  int t = threadIdx.x;
  int i = blockIdx.x * 256 + t;
  int v = (i < NN) ? counts[i] : 0;
  s[t] = v;
  __syncthreads();
  for (int off = 1; off < 256; off <<= 1) {
    int add = (t >= off) ? s[t - off] : 0;
    __syncthreads();
    s[t] += add;
    __syncthreads();
  }
  int rp = boff[blockIdx.x] + s[t] - v;  // exclusive
  if (i < NN) {
    row_ptr[i] = rp;
    cursor[i] = rp;
  }
}

__global__ __launch_bounds__(256) void k_fill(const int* __restrict__ src,
                                              const int* __restrict__ dst,
                                              int* __restrict__ cursor,
                                              int* __restrict__ csr_src) {
  int e = blockIdx.x * 256 + threadIdx.x;
  if (e < NE) {
    int d = dst[e];
    int pos = atomicAdd(&cursor[d], 1);
    csr_src[pos] = src[e];
  }
}

// GEMM inner: spill-safe, statically indexed, hoisting bounded per m-iter.
#define GEMM_CHUNK(ZS, LDIM, KC, ACC, W4)                              \
  {                                                                    \
    _Pragma("unroll") for (int m = 0; m < 16; m++) {                   \
      const float* zr = (ZS) + (wave * 16 + m) * (LDIM) + (KC);        \
      float a = ACC[m];                                                \
      _Pragma("unroll") for (int q = 0; q < 8; q++) {                  \
        float4 zv = *(const float4*)(zr + q * 4);                      \
        a = fmaf(zv.x, W4[q].x, a);                                    \
        a = fmaf(zv.y, W4[q].y, a);                                    \
        a = fmaf(zv.z, W4[q].z, a);                                    \
        a = fmaf(zv.w, W4[q].w, a);                                    \
      }                                                                \
      ACC[m] = a;                                                      \
      __builtin_amdgcn_sched_barrier(0);                               \
    }                                                                  \
  }

// pack feature pair into f16x2 word and store hn2 (even lanes write)
__device__ __forceinline__ void store_hn2(unsigned* __restrict__ hn2, int node,
                                          int lane, float y) {
  float partner = __shfl_xor(y, 1, 64);
  if (!(lane & 1)) {
    __half2 hh = __floats2half2_rn(y, partner);  // lo=feat(lane), hi=feat(lane+1)
    hn2[node * (HD / 2) + (lane >> 1)] = *reinterpret_cast<unsigned*>(&hh);
  }
}

// ---------- encoder: h = x @ W^T + b ; hn2 = f16(relu(LN_0(h))) ----------
__global__ __launch_bounds__(256) void k_encoder(
    const float* __restrict__ x, const float* __restrict__ W,
    const float* __restrict__ bias, const float* __restrict__ lng,
    const float* __restrict__ lnb, float* __restrict__ h,
    unsigned* __restrict__ hn2) {
  __shared__ float xs[64 * DIN];
  const int tid = threadIdx.x, lane = tid & 63, wave = tid >> 6;
  const int nbase = blockIdx.x * 64;
  const int nvalid = min(64, NN - nbase);
  const float4* xg = (const float4*)(x + (size_t)nbase * DIN);
  for (int i = tid; i < nvalid * (DIN / 4); i += 256) ((float4*)xs)[i] = xg[i];
  __syncthreads();

  float acc[16];
  const float bv = bias[lane];
#pragma unroll
  for (int m = 0; m < 16; m++) acc[m] = bv;
  const float* wrow = W + lane * DIN;
#pragma unroll 1
  for (int kc = 0; kc < DIN; kc += 32) {
    float4 w4[8];
#pragma unroll
    for (int q = 0; q < 8; q++) w4[q] = *(const float4*)(wrow + kc + q * 4);
    GEMM_CHUNK(xs, DIN, kc, acc, w4)
  }

  const float g = lng[lane], bb = lnb[lane];
#pragma unroll
  for (int m = 0; m < 16; m++) {
    int nl = wave * 16 + m;
    int node = nbase + nl;
    float v = acc[m];
    float mu = wave_sum64(v) * (1.f / 64.f);
    float d = v - mu;
    float var = wave_sum64(d * d) * (1.f / 64.f);
    float y = fmaxf(d * rsqrtf(var + 1e-5f) * g + bb, 0.f);
    if (nl < nvalid) h[(size_t)node * HD + lane] = v;
    if (nl < nvalid) store_hn2(hn2, node, lane, y);
  }
}

#define ACC4(U)                          \
  {                                      \
    float2 f0 = unpack_h2((U).x);        \
    float2 f1 = unpack_h2((U).y);        \
    acc.x += f0.x;                       \
    acc.y += f0.y;                       \
    acc.z += f1.x;                       \
    acc.w += f1.y;                       \
  }

// ---------- fused layer: gather (f16) + MLP + residual + LN ----------------
// Gather: each quarter-wave owns one node (4 concurrent per wave), edge loop
// unrolled x4 -> 16 row-loads in flight per wave. No shuffles, no barriers.
// hn2_in and hn2_out MUST be distinct buffers (cross-block race otherwise).
__global__ __launch_bounds__(256) void k_layer(
    const unsigned* __restrict__ hn2_in, float* __restrict__ h,
    unsigned* __restrict__ hn2_out, const int* __restrict__ row_ptr,
    const int* __restrict__ csr_src, const float* __restrict__ eps_arr,
    int layer, const float* __restrict__ w1, const float* __restrict__ b1,
    const float* __restrict__ g1, const float* __restrict__ bb1,
    const float* __restrict__ m1, const float* __restrict__ v1,
    const float* __restrict__ w2, const float* __restrict__ b2,
    const float* __restrict__ g2, const float* __restrict__ bb2,
    const float* __restrict__ m2, const float* __restrict__ v2,
    const float* __restrict__ lng, const float* __restrict__ lnb, int do_ln) {
  __shared__ float zs[64 * HD];
  __shared__ float z1s[64 * HD];
  const int tid = threadIdx.x, lane = tid & 63, wave = tid >> 6;
  const int qtr = lane >> 4, ql = lane & 15;
  const int nbase = blockIdx.x * 64;
  const float e = 1.f + eps_arr[layer];
  const uint2* hnv = (const uint2*)hn2_in;  // 16 uint2 per node row

#pragma unroll 1
  for (int g = 0; g < 4; g++) {
    const int nl = wave * 16 + g * 4 + qtr;  // local row in zs
    const int node = nbase + nl;
    const bool valid = node < NN;
    int s0 = 0, s1 = 0;
    if (valid) {
      s0 = row_ptr[node];
      s1 = row_ptr[node + 1];
    }
    float4 acc = make_float4(0.f, 0.f, 0.f, 0.f);
    if (valid) {  // self term
      uint2 u = hnv[(size_t)node * 16 + ql];
      float2 f0 = unpack_h2(u.x), f1 = unpack_h2(u.y);
      acc.x = e * f0.x;
      acc.y = e * f0.y;
      acc.z = e * f1.x;
      acc.w = e * f1.y;
    }
    int j = s0;
    for (; j + 4 <= s1; j += 4) {
      int sA = csr_src[j], sB = csr_src[j + 1];
      int sC = csr_src[j + 2], sD = csr_src[j + 3];
      uint2 uA = hnv[(size_t)sA * 16 + ql];
      uint2 uB = hnv[(size_t)sB * 16 + ql];
      uint2 uC = hnv[(size_t)sC * 16 + ql];
      uint2 uD = hnv[(size_t)sD * 16 + ql];
      ACC4(uA)
      ACC4(uB)
      ACC4(uC)
      ACC4(uD)
    }
    for (; j < s1; j++) {
      int s = csr_src[j];
      uint2 u = hnv[(size_t)s * 16 + ql];
      ACC4(u)
    }
    if (valid) *(float4*)(zs + nl * HD + 4 * ql) = acc;
  }
  // no __syncthreads: each wave only writes/reads its own 16 zs rows

  const float a1 = g1[lane] * rsqrtf(v1[lane] + 1e-5f);
  const float c1 = (b1[lane] - m1[lane]) * a1 + bb1[lane];
  float acc[16];
#pragma unroll
  for (int m = 0; m < 16; m++) acc[m] = 0.f;
  {
    const float* wrow = w1 + lane * HD;
#pragma unroll 1
    for (int kc = 0; kc < HD; kc += 32) {
      float4 w4[8];
#pragma unroll
      for (int q = 0; q < 8; q++) w4[q] = *(const float4*)(wrow + kc + q * 4);
      GEMM_CHUNK(zs, HD, kc, acc, w4)
    }
  }
#pragma unroll
  for (int m = 0; m < 16; m++) {
    float z1v = fmaxf(fmaf(acc[m], a1, c1), 0.f);
    z1s[(wave * 16 + m) * HD + lane] = z1v;
  }

  const float a2 = g2[lane] * rsqrtf(v2[lane] + 1e-5f);
  const float c2 = (b2[lane] - m2[lane]) * a2 + bb2[lane];
#pragma unroll
  for (int m = 0; m < 16; m++) acc[m] = 0.f;
  {
    const float* wrow = w2 + lane * HD;
#pragma unroll 1
    for (int kc = 0; kc < HD; kc += 32) {
      float4 w4[8];
#pragma unroll
      for (int q = 0; q < 8; q++) w4[q] = *(const float4*)(wrow + kc + q * 4);
      GEMM_CHUNK(z1s, HD, kc, acc, w4)
    }
  }

  const int nvalid = min(64, NN - nbase);
  const float g = lng[lane], bbv = lnb[lane];
#pragma unroll
  for (int m = 0; m < 16; m++) {
    int nl = wave * 16 + m;
    int node = nbase + nl;
    float hv = (nl < nvalid) ? h[(size_t)node * HD + lane] : 0.f;
    float z2v = fmaxf(fmaf(acc[m], a2, c2), 0.f);
    float v = hv + z2v;
    if (nl < nvalid) h[(size_t)node * HD + lane] = v;
    if (do_ln) {
      float mu = wave_sum64(v) * (1.f / 64.f);
      float d = v - mu;
      float var = wave_sum64(d * d) * (1.f / 64.f);
      float y = fmaxf(d * rsqrtf(var + 1e-5f) * g + bbv, 0.f);
      if (nl < nvalid) store_hn2(hn2_out, node, lane, y);
    }
  }
}

// ---------- pooling ----------
__global__ __launch_bounds__(256) void k_pool(const float* __restrict__ h,
                                              const int* __restrict__ batch,
                                              float* __restrict__ sums,
                                              float* __restrict__ cnt) {
  const int lane = threadIdx.x & 63;
  const int gw = blockIdx.x * 4 + (threadIdx.x >> 6);
  const int base = gw * 64;
  if (base >= NN) return;
  const int end = min(base + 64, NN);
  float acc = 0.f;
  int cur = batch[base];
  int runlen = 0;
  for (int n = base; n < end; n++) {
    int g = batch[n];
    if (g != cur) {
      atomicAdd(&sums[cur * HD + lane], acc);
      if (lane == 0) atomicAdd(&cnt[cur], (float)runlen);
      acc = 0.f;
      runlen = 0;
      cur = g;
    }
    acc += h[(size_t)n * HD + lane];
    runlen++;
  }
  atomicAdd(&sums[cur * HD + lane], acc);
  if (lane == 0) atomicAdd(&cnt[cur], (float)runlen);
}

__global__ __launch_bounds__(256) void k_div(const float* __restrict__ sums,
                                             const float* __restrict__ cnt,
                                             float* __restrict__ out) {
  int i = blockIdx.x * 256 + threadIdx.x;
  if (i < NG * HD) out[i] = sums[i] / fmaxf(cnt[i >> 6], 1.f);
}

// ---------- launch ----------
extern "C" void kernel_launch(void* const* d_in, const int* in_sizes, int n_in,
                              void* d_out, int out_size, void* d_ws,
                              size_t ws_size, hipStream_t stream) {
  const float* x = (const float*)d_in[0];
  const float* node_w = (const float*)d_in[1];
  const float* node_b = (const float*)d_in[2];
  const float* ln_g = (const float*)d_in[3];
  const float* ln_b = (const float*)d_in[4];
  const float* eps = (const float*)d_in[5];
  const float* w1 = (const float*)d_in[6];
  const float* b1 = (const float*)d_in[7];
  const float* bn1_g = (const float*)d_in[8];
  const float* bn1_b = (const float*)d_in[9];
  const float* bn1_m = (const float*)d_in[10];
  const float* bn1_v = (const float*)d_in[11];
  const float* w2 = (const float*)d_in[12];
  const float* b2 = (const float*)d_in[13];
  const float* bn2_g = (const float*)d_in[14];
  const float* bn2_b = (const float*)d_in[15];
  const float* bn2_m = (const float*)d_in[16];
  const float* bn2_v = (const float*)d_in[17];
  const int* edge_index = (const int*)d_in[18];
  const int* batch = (const int*)d_in[19];
  float* out = (float*)d_out;

  char* ws = (char*)d_ws;
  size_t off = 0;
  auto carve = [&](size_t bytes) {
    void* p = ws + off;
    off += (bytes + 255) & ~(size_t)255;
    return p;
  };
  const size_t NHB = (size_t)NN * HD * sizeof(float);
  float* h = (float*)carve(NHB);
  unsigned* hn2a = (unsigned*)carve((size_t)NN * (HD / 2) * sizeof(unsigned));
  unsigned* hn2b = (unsigned*)carve((size_t)NN * (HD / 2) * sizeof(unsigned));
  int* csr_src = (int*)carve((size_t)NE * sizeof(int));
  int* row_ptr = (int*)carve((size_t)(NN + 1) * sizeof(int));
  int* cursor = (int*)carve((size_t)NN * sizeof(int));
  int* counts = (int*)carve((size_t)NN * sizeof(int));
  int* bsum = (int*)carve(512 * sizeof(int));
  int* boff = (int*)carve(512 * sizeof(int));
  float* sums = (float*)carve((size_t)NG * HD * sizeof(float));
  float* cnt = (float*)carve((size_t)NG * sizeof(float));

  const int NB = (NN + 255) / 256;  // 391

  hipMemsetAsync(counts, 0, (size_t)NN * sizeof(int), stream);
  hipMemsetAsync(sums, 0, (size_t)NG * HD * sizeof(float), stream);
  hipMemsetAsync(cnt, 0, (size_t)NG * sizeof(float), stream);

  const int* e_src = edge_index;
  const int* e_dst = edge_index + NE;

  k_count<<<(NE + 255) / 256, 256, 0, stream>>>(e_dst, counts);
  k_bsum<<<NB, 256, 0, stream>>>(counts, bsum);
  k_scanb<<<1, 512, 0, stream>>>(bsum, boff, NB, row_ptr);
  k_scan3<<<NB, 256, 0, stream>>>(counts, boff, row_ptr, cursor);
  k_fill<<<(NE + 255) / 256, 256, 0, stream>>>(e_src, e_dst, cursor, csr_src);

  k_encoder<<<(NN + 63) / 64, 256, 0, stream>>>(x, node_w, node_b, ln_g, ln_b,
                                                h, hn2a);

  for (int l = 0; l < NL; l++) {
    int do_ln = (l < NL - 1) ? 1 : 0;
    const float* lg = do_ln ? (ln_g + (l + 1) * HD) : ln_g;
    const float* lb = do_ln ? (ln_b + (l + 1) * HD) : ln_b;
    const unsigned* hin = (l & 1) ? hn2b : hn2a;
    unsigned* hout = (l & 1) ? hn2a : hn2b;
    k_layer<<<(NN + 63) / 64, 256, 0, stream>>>(
        hin, h, hout, row_ptr, csr_src, eps, l, w1 + (size_t)l * HD * HD,
        b1 + l * HD, bn1_g + l * HD, bn1_b + l * HD, bn1_m + l * HD,
        bn1_v + l * HD, w2 + (size_t)l * HD * HD, b2 + l * HD, bn2_g + l * HD,
        bn2_b + l * HD, bn2_m + l * HD, bn2_v + l * HD, lg, lb, do_ln);
  }

  k_pool<<<NB, 256, 0, stream>>>(h, batch, sums, cnt);
  k_div<<<(NG * HD + 255) / 256, 256, 0, stream>>>(sums, cnt, out);
}

// Round 6
// 743.066 us; speedup vs baseline: 4.4807x; 1.0583x over previous
//
#include <hip/hip_runtime.h>
#include <hip/hip_fp16.h>

#define NN 100000
#define NE 1600000
#define DIN 128
#define HD 64
#define NL 4
#define NG 64
#define FILL_R 8   // dst ranges (XCD-affine via blockIdx%8)
#define FILL_B 64  // blocks per range

// ---------- helpers ----------
__device__ __forceinline__ float wave_sum64(float v) {
#pragma unroll
  for (int off = 1; off < 64; off <<= 1) v += __shfl_xor(v, off, 64);
  return v;
}

__device__ __forceinline__ float2 unpack_h2(unsigned w) {
  __half2 hh = *reinterpret_cast<__half2*>(&w);
  return __half22float2(hh);
}

// ---------- CSR build ----------
__global__ __launch_bounds__(256) void k_count(const int* __restrict__ dst,
                                               int* __restrict__ counts) {
  int e = blockIdx.x * 256 + threadIdx.x;
  if (e < NE) atomicAdd(&counts[dst[e]], 1);
}

__global__ __launch_bounds__(256) void k_bsum(const int* __restrict__ counts,
                                              int* __restrict__ bsum) {
  __shared__ int s[256];
  int tid = threadIdx.x;
  int i = blockIdx.x * 256 + tid;
  s[tid] = (i < NN) ? counts[i] : 0;
  __syncthreads();
#pragma unroll
  for (int off = 128; off > 0; off >>= 1) {
    if (tid < off) s[tid] += s[tid + off];
    __syncthreads();
  }
  if (tid == 0) bsum[blockIdx.x] = s[0];
}

__global__ __launch_bounds__(512) void k_scanb(const int* __restrict__ bsum,
                                               int* __restrict__ boff, int nb,
                                               int* __restrict__ row_ptr) {
  __shared__ int s[512];
  int t = threadIdx.x;
  int v = (t < nb) ? bsum[t] : 0;
  s[t] = v;
  __syncthreads();
  for (int off = 1; off < 512; off <<= 1) {
    int add = (t >= off) ? s[t - off] : 0;
    __syncthreads();
    s[t] += add;
    __syncthreads();
  }
  if (t < nb) boff[t] = s[t] - v;  // exclusive
  if (t == 0) row_ptr[NN] = NE;
}

__global__ __launch_bounds__(256) void k_scan3(const int* __restrict__ counts,
                                               const int* __restrict__ boff,
                                               int* __restrict__ row_ptr,
                                               int* __restrict__ cursor) {
  __shared__ int s[256];
  int t = threadIdx.x;
  int i = blockIdx.x * 256 + t;
  int v = (i < NN) ? counts[i] : 0;
  s[t] = v;
  __syncthreads();
  for (int off = 1; off < 256; off <<= 1) {
    int add = (t >= off) ? s[t - off] : 0;
    __syncthreads();
    s[t] += add;
    __syncthreads();
  }
  int rp = boff[blockIdx.x] + s[t] - v;  // exclusive
  if (i < NN) {
    row_ptr[i] = rp;
    cursor[i] = rp;
  }
}

// Range-partitioned fill: block handles dst range [lo,hi) over one edge
// slice. All blocks of a range land on (heuristically) one XCD via %8 ->
// its ~0.8 MB csr region accumulates in that L2 -> writes coalesce.
// Correctness does not depend on the XCD mapping (G16-safe).
__global__ __launch_bounds__(256) void k_fill(const int* __restrict__ src,
                                              const int* __restrict__ dst,
                                              int* __restrict__ cursor,
                                              int* __restrict__ csr_src) {
  const int range = blockIdx.x % FILL_R;
  const int sub = blockIdx.x / FILL_R;
  const int lo = range * (NN / FILL_R);
  const int hi = lo + (NN / FILL_R);
  const int e0 = sub * (NE / FILL_B);
  const int e1 = e0 + (NE / FILL_B);
  for (int e = e0 + threadIdx.x; e < e1; e += 256) {
    int d = dst[e];
    if (d >= lo && d < hi) {
      int pos = atomicAdd(&cursor[d], 1);
      csr_src[pos] = src[e];
    }
  }
}

// GEMM inner: spill-safe, statically indexed, hoisting bounded per m-iter.
#define GEMM_CHUNK(ZS, LDIM, KC, ACC, W4)                              \
  {                                                                    \
    _Pragma("unroll") for (int m = 0; m < 16; m++) {                   \
      const float* zr = (ZS) + (wave * 16 + m) * (LDIM) + (KC);        \
      float a = ACC[m];                                                \
      _Pragma("unroll") for (int q = 0; q < 8; q++) {                  \
        float4 zv = *(const float4*)(zr + q * 4);                      \
        a = fmaf(zv.x, W4[q].x, a);                                    \
        a = fmaf(zv.y, W4[q].y, a);                                    \
        a = fmaf(zv.z, W4[q].z, a);                                    \
        a = fmaf(zv.w, W4[q].w, a);                                    \
      }                                                                \
      ACC[m] = a;                                                      \
      __builtin_amdgcn_sched_barrier(0);                               \
    }                                                                  \
  }

// pack feature pair into f16x2 word and store hn2 (even lanes write)
__device__ __forceinline__ void store_hn2(unsigned* __restrict__ hn2, int node,
                                          int lane, float y) {
  float partner = __shfl_xor(y, 1, 64);
  if (!(lane & 1)) {
    __half2 hh = __floats2half2_rn(y, partner);
    hn2[node * (HD / 2) + (lane >> 1)] = *reinterpret_cast<unsigned*>(&hh);
  }
}

// ---------- encoder: h = x @ W^T + b ; hn2 = f16(relu(LN_0(h))) ----------
__global__ __launch_bounds__(256) void k_encoder(
    const float* __restrict__ x, const float* __restrict__ W,
    const float* __restrict__ bias, const float* __restrict__ lng,
    const float* __restrict__ lnb, float* __restrict__ h,
    unsigned* __restrict__ hn2) {
  __shared__ float xs[64 * DIN];
  const int tid = threadIdx.x, lane = tid & 63, wave = tid >> 6;
  const int nbase = blockIdx.x * 64;
  const int nvalid = min(64, NN - nbase);
  const float4* xg = (const float4*)(x + (size_t)nbase * DIN);
  for (int i = tid; i < nvalid * (DIN / 4); i += 256) ((float4*)xs)[i] = xg[i];
  __syncthreads();

  float acc[16];
  const float bv = bias[lane];
#pragma unroll
  for (int m = 0; m < 16; m++) acc[m] = bv;
  const float* wrow = W + lane * DIN;
#pragma unroll 1
  for (int kc = 0; kc < DIN; kc += 32) {
    float4 w4[8];
#pragma unroll
    for (int q = 0; q < 8; q++) w4[q] = *(const float4*)(wrow + kc + q * 4);
    GEMM_CHUNK(xs, DIN, kc, acc, w4)
  }

  const float g = lng[lane], bb = lnb[lane];
#pragma unroll
  for (int m = 0; m < 16; m++) {
    int nl = wave * 16 + m;
    int node = nbase + nl;
    float v = acc[m];
    float mu = wave_sum64(v) * (1.f / 64.f);
    float d = v - mu;
    float var = wave_sum64(d * d) * (1.f / 64.f);
    float y = fmaxf(d * rsqrtf(var + 1e-5f) * g + bb, 0.f);
    if (nl < nvalid) h[(size_t)node * HD + lane] = v;
    if (nl < nvalid) store_hn2(hn2, node, lane, y);
  }
}

#define ACC4(U)                          \
  {                                      \
    float2 f0 = unpack_h2((U).x);        \
    float2 f1 = unpack_h2((U).y);        \
    acc.x += f0.x;                       \
    acc.y += f0.y;                       \
    acc.z += f1.x;                       \
    acc.w += f1.y;                       \
  }

// ---------- fused layer: gather (f16) + MLP + residual + LN ----------------
// Quarter-wave owns one node; edge loop unrolled x8 (8 idx + 8 row loads in
// flight per quarter-wave). z1 aliases zs (per-wave read-then-write is
// sequential) -> LDS 16 KB -> 8 blocks/CU. Zero barriers.
// hn2_in and hn2_out MUST be distinct buffers (cross-block race otherwise).
__global__ __launch_bounds__(256) void k_layer(
    const unsigned* __restrict__ hn2_in, float* __restrict__ h,
    unsigned* __restrict__ hn2_out, const int* __restrict__ row_ptr,
    const int* __restrict__ csr_src, const float* __restrict__ eps_arr,
    int layer, const float* __restrict__ w1, const float* __restrict__ b1,
    const float* __restrict__ g1, const float* __restrict__ bb1,
    const float* __restrict__ m1, const float* __restrict__ v1,
    const float* __restrict__ w2, const float* __restrict__ b2,
    const float* __restrict__ g2, const float* __restrict__ bb2,
    const float* __restrict__ m2, const float* __restrict__ v2,
    const float* __restrict__ lng, const float* __restrict__ lnb, int do_ln) {
  __shared__ float zs[64 * HD];  // reused for z1 after GEMM1
  const int tid = threadIdx.x, lane = tid & 63, wave = tid >> 6;
  const int qtr = lane >> 4, ql = lane & 15;
  const int nbase = blockIdx.x * 64;
  const float e = 1.f + eps_arr[layer];
  const uint2* hnv = (const uint2*)hn2_in;  // 16 uint2 per node row

#pragma unroll 1
  for (int g = 0; g < 4; g++) {
    const int nl = wave * 16 + g * 4 + qtr;  // local row in zs
    const int node = nbase + nl;
    const bool valid = node < NN;
    int s0 = 0, s1 = 0;
    if (valid) {
      s0 = row_ptr[node];
      s1 = row_ptr[node + 1];
    }
    float4 acc = make_float4(0.f, 0.f, 0.f, 0.f);
    if (valid) {  // self term
      uint2 u = hnv[(size_t)node * 16 + ql];
      float2 f0 = unpack_h2(u.x), f1 = unpack_h2(u.y);
      acc.x = e * f0.x;
      acc.y = e * f0.y;
      acc.z = e * f1.x;
      acc.w = e * f1.y;
    }
    int j = s0;
    for (; j + 8 <= s1; j += 8) {
      int s_[8];
      uint2 u_[8];
#pragma unroll
      for (int t = 0; t < 8; t++) s_[t] = csr_src[j + t];
#pragma unroll
      for (int t = 0; t < 8; t++) u_[t] = hnv[(size_t)s_[t] * 16 + ql];
#pragma unroll
      for (int t = 0; t < 8; t++) ACC4(u_[t])
    }
    if (j + 4 <= s1) {
      int s_[4];
      uint2 u_[4];
#pragma unroll
      for (int t = 0; t < 4; t++) s_[t] = csr_src[j + t];
#pragma unroll
      for (int t = 0; t < 4; t++) u_[t] = hnv[(size_t)s_[t] * 16 + ql];
#pragma unroll
      for (int t = 0; t < 4; t++) ACC4(u_[t])
      j += 4;
    }
    for (; j < s1; j++) {
      int s = csr_src[j];
      uint2 u = hnv[(size_t)s * 16 + ql];
      ACC4(u)
    }
    if (valid) *(float4*)(zs + nl * HD + 4 * ql) = acc;
  }
  // no __syncthreads: each wave only writes/reads its own 16 zs rows

  const float a1 = g1[lane] * rsqrtf(v1[lane] + 1e-5f);
  const float c1 = (b1[lane] - m1[lane]) * a1 + bb1[lane];
  float acc[16];
#pragma unroll
  for (int m = 0; m < 16; m++) acc[m] = 0.f;
  {
    const float* wrow = w1 + lane * HD;
#pragma unroll 1
    for (int kc = 0; kc < HD; kc += 32) {
      float4 w4[8];
#pragma unroll
      for (int q = 0; q < 8; q++) w4[q] = *(const float4*)(wrow + kc + q * 4);
      GEMM_CHUNK(zs, HD, kc, acc, w4)
    }
  }
  // write z1 back into zs rows (all reads of this wave's rows are done)
#pragma unroll
  for (int m = 0; m < 16; m++) {
    float z1v = fmaxf(fmaf(acc[m], a1, c1), 0.f);
    zs[(wave * 16 + m) * HD + lane] = z1v;
  }

  const float a2 = g2[lane] * rsqrtf(v2[lane] + 1e-5f);
  const float c2 = (b2[lane] - m2[lane]) * a2 + bb2[lane];
#pragma unroll
  for (int m = 0; m < 16; m++) acc[m] = 0.f;
  {
    const float* wrow = w2 + lane * HD;
#pragma unroll 1
    for (int kc = 0; kc < HD; kc += 32) {
      float4 w4[8];
#pragma unroll
      for (int q = 0; q < 8; q++) w4[q] = *(const float4*)(wrow + kc + q * 4);
      GEMM_CHUNK(zs, HD, kc, acc, w4)
    }
  }

  const int nvalid = min(64, NN - nbase);
  const float g = lng[lane], bbv = lnb[lane];
#pragma unroll
  for (int m = 0; m < 16; m++) {
    int nl = wave * 16 + m;
    int node = nbase + nl;
    float hv = (nl < nvalid) ? h[(size_t)node * HD + lane] : 0.f;
    float z2v = fmaxf(fmaf(acc[m], a2, c2), 0.f);
    float v = hv + z2v;
    if (nl < nvalid) h[(size_t)node * HD + lane] = v;
    if (do_ln) {
      float mu = wave_sum64(v) * (1.f / 64.f);
      float d = v - mu;
      float var = wave_sum64(d * d) * (1.f / 64.f);
      float y = fmaxf(d * rsqrtf(var + 1e-5f) * g + bbv, 0.f);
      if (nl < nvalid) store_hn2(hn2_out, node, lane, y);
    }
  }
}

// ---------- pooling ----------
__global__ __launch_bounds__(256) void k_pool(const float* __restrict__ h,
                                              const int* __restrict__ batch,
                                              float* __restrict__ sums,
                                              float* __restrict__ cnt) {
  const int lane = threadIdx.x & 63;
  const int gw = blockIdx.x * 4 + (threadIdx.x >> 6);
  const int base = gw * 64;
  if (base >= NN) return;
  const int end = min(base + 64, NN);
  float acc = 0.f;
  int cur = batch[base];
  int runlen = 0;
  for (int n = base; n < end; n++) {
    int g = batch[n];
    if (g != cur) {
      atomicAdd(&sums[cur * HD + lane], acc);
      if (lane == 0) atomicAdd(&cnt[cur], (float)runlen);
      acc = 0.f;
      runlen = 0;
      cur = g;
    }
    acc += h[(size_t)n * HD + lane];
    runlen++;
  }
  atomicAdd(&sums[cur * HD + lane], acc);
  if (lane == 0) atomicAdd(&cnt[cur], (float)runlen);
}

__global__ __launch_bounds__(256) void k_div(const float* __restrict__ sums,
                                             const float* __restrict__ cnt,
                                             float* __restrict__ out) {
  int i = blockIdx.x * 256 + threadIdx.x;
  if (i < NG * HD) out[i] = sums[i] / fmaxf(cnt[i >> 6], 1.f);
}

// ---------- launch ----------
extern "C" void kernel_launch(void* const* d_in, const int* in_sizes, int n_in,
                              void* d_out, int out_size, void* d_ws,
                              size_t ws_size, hipStream_t stream) {
  const float* x = (const float*)d_in[0];
  const float* node_w = (const float*)d_in[1];
  const float* node_b = (const float*)d_in[2];
  const float* ln_g = (const float*)d_in[3];
  const float* ln_b = (const float*)d_in[4];
  const float* eps = (const float*)d_in[5];
  const float* w1 = (const float*)d_in[6];
  const float* b1 = (const float*)d_in[7];
  const float* bn1_g = (const float*)d_in[8];
  const float* bn1_b = (const float*)d_in[9];
  const float* bn1_m = (const float*)d_in[10];
  const float* bn1_v = (const float*)d_in[11];
  const float* w2 = (const float*)d_in[12];
  const float* b2 = (const float*)d_in[13];
  const float* bn2_g = (const float*)d_in[14];
  const float* bn2_b = (const float*)d_in[15];
  const float* bn2_m = (const float*)d_in[16];
  const float* bn2_v = (const float*)d_in[17];
  const int* edge_index = (const int*)d_in[18];
  const int* batch = (const int*)d_in[19];
  float* out = (float*)d_out;

  char* ws = (char*)d_ws;
  size_t off = 0;
  auto carve = [&](size_t bytes) {
    void* p = ws + off;
    off += (bytes + 255) & ~(size_t)255;
    return p;
  };
  const size_t NHB = (size_t)NN * HD * sizeof(float);
  float* h = (float*)carve(NHB);
  unsigned* hn2a = (unsigned*)carve((size_t)NN * (HD / 2) * sizeof(unsigned));
  unsigned* hn2b = (unsigned*)carve((size_t)NN * (HD / 2) * sizeof(unsigned));
  int* csr_src = (int*)carve((size_t)NE * sizeof(int));
  int* row_ptr = (int*)carve((size_t)(NN + 1) * sizeof(int));
  int* cursor = (int*)carve((size_t)NN * sizeof(int));
  int* counts = (int*)carve((size_t)NN * sizeof(int));
  int* bsum = (int*)carve(512 * sizeof(int));
  int* boff = (int*)carve(512 * sizeof(int));
  float* sums = (float*)carve((size_t)NG * HD * sizeof(float));
  float* cnt = (float*)carve((size_t)NG * sizeof(float));

  const int NB = (NN + 255) / 256;  // 391

  hipMemsetAsync(counts, 0, (size_t)NN * sizeof(int), stream);
  hipMemsetAsync(sums, 0, (size_t)NG * HD * sizeof(float), stream);
  hipMemsetAsync(cnt, 0, (size_t)NG * sizeof(float), stream);

  const int* e_src = edge_index;
  const int* e_dst = edge_index + NE;

  k_count<<<(NE + 255) / 256, 256, 0, stream>>>(e_dst, counts);
  k_bsum<<<NB, 256, 0, stream>>>(counts, bsum);
  k_scanb<<<1, 512, 0, stream>>>(bsum, boff, NB, row_ptr);
  k_scan3<<<NB, 256, 0, stream>>>(counts, boff, row_ptr, cursor);
  k_fill<<<FILL_R * FILL_B, 256, 0, stream>>>(e_src, e_dst, cursor, csr_src);

  k_encoder<<<(NN + 63) / 64, 256, 0, stream>>>(x, node_w, node_b, ln_g, ln_b,
                                                h, hn2a);

  for (int l = 0; l < NL; l++) {
    int do_ln = (l < NL - 1) ? 1 : 0;
    const float* lg = do_ln ? (ln_g + (l + 1) * HD) : ln_g;
    const float* lb = do_ln ? (ln_b + (l + 1) * HD) : ln_b;
    const unsigned* hin = (l & 1) ? hn2b : hn2a;
    unsigned* hout = (l & 1) ? hn2a : hn2b;
    k_layer<<<(NN + 63) / 64, 256, 0, stream>>>(
        hin, h, hout, row_ptr, csr_src, eps, l, w1 + (size_t)l * HD * HD,
        b1 + l * HD, bn1_g + l * HD, bn1_b + l * HD, bn1_m + l * HD,
        bn1_v + l * HD, w2 + (size_t)l * HD * HD, b2 + l * HD, bn2_g + l * HD,
        bn2_b + l * HD, bn2_m + l * HD, bn2_v + l * HD, lg, lb, do_ln);
  }

  k_pool<<<NB, 256, 0, stream>>>(h, batch, sums, cnt);
  k_div<<<(NG * HD + 255) / 256, 256, 0, stream>>>(sums, cnt, out);
}